// Round 3
// baseline (43357.547 us; speedup 1.0000x reference)
//
#include <hip/hip_runtime.h>
#include <math.h>

// Problem constants
#define Vv 8000
#define Ee 256
#define Hh 256
#define Tt 4
#define Bb 64
#define Ss 512

#define EPROJ_PER_DIR (Vv * 1024)   // 8,192,000 floats per direction
#define WMAT_PER_DIR  (Ee * 1024)   // 262,144 floats per direction

__device__ __forceinline__ float sigm(float x) { return 1.f / (1.f + expf(-x)); }

// ---------------------------------------------------------------------------
// prep: repack weights.
//   WihP [dir][e][j']  j' = u*4+g  <-> gate-row g*256+u   (GEMM B-matrix)
//   Whh4 [dir][k][u*4+g] = Whh[g*256+u][k]                (recurrent)
//   bP   [dir][j']     = b[g*256+u]
//   WlinT[dir][t][u]   = Wlin[t][dir*256+u]               (emission, transposed)
// ---------------------------------------------------------------------------
__global__ void prep_kernel(const float* __restrict__ Wih_f, const float* __restrict__ Whh_f,
                            const float* __restrict__ b_f,
                            const float* __restrict__ Wih_b, const float* __restrict__ Whh_b,
                            const float* __restrict__ b_b,
                            const float* __restrict__ Wlin,
                            float* __restrict__ WihP, float* __restrict__ Whh4,
                            float* __restrict__ bP, float* __restrict__ WlinT)
{
    int tid = blockIdx.x * blockDim.x + threadIdx.x;   // [0, 2*262144)
    int dir = tid >> 18;
    int r   = tid & 262143;
    int k   = r >> 10;        // 0..255 (e or k)
    int jp  = r & 1023;       // j'
    int u   = jp >> 2;
    int g   = jp & 3;
    int row = g * 256 + u;    // original gate row
    const float* Wih = dir ? Wih_b : Wih_f;
    const float* Whh = dir ? Whh_b : Whh_f;
    const float* bv  = dir ? b_b   : b_f;
    WihP[dir * WMAT_PER_DIR + k * 1024 + jp] = Wih[row * 256 + k];
    Whh4[dir * WMAT_PER_DIR + k * 1024 + jp] = Whh[row * 256 + k];
    if (r < 1024) {
        bP[dir * 1024 + jp] = bv[row];
        int uu = r >> 2, tt = r & 3;
        WlinT[dir * 1024 + tt * 256 + uu] = Wlin[tt * (2 * Hh) + dir * 256 + uu];
    }
}

// ---------------------------------------------------------------------------
// embproj GEMM: embproj[dir][v][j'] = sum_e emb[v][e]*WihP[dir][e][j'] + bP[dir][j']
// ---------------------------------------------------------------------------
#define BM 64
#define BN 128
#define BK 16
__global__ __launch_bounds__(256) void embproj_gemm(const float* __restrict__ emb,
                                                    const float* __restrict__ WihP,
                                                    const float* __restrict__ bP,
                                                    float* __restrict__ embproj)
{
    int dir = blockIdx.z;
    const float* Bmat = WihP + dir * WMAT_PER_DIR;
    float* C = embproj + (size_t)dir * EPROJ_PER_DIR;
    int m0 = blockIdx.x * BM;
    int n0 = blockIdx.y * BN;

    __shared__ float As[BK][BM];
    __shared__ float Bs[BK][BN];

    int t = threadIdx.x;
    int tm = (t & 15) * 4;
    int tn = (t >> 4) * 8;
    float acc[4][8];
    #pragma unroll
    for (int i = 0; i < 4; ++i)
        #pragma unroll
        for (int j = 0; j < 8; ++j) acc[i][j] = 0.f;

    for (int k0 = 0; k0 < Ee; k0 += BK) {
        {   // A tile 64x16
            int row = t >> 2, seg = t & 3;
            float4 a4 = *(const float4*)(&emb[(size_t)(m0 + row) * Ee + k0 + seg * 4]);
            As[seg * 4 + 0][row] = a4.x;
            As[seg * 4 + 1][row] = a4.y;
            As[seg * 4 + 2][row] = a4.z;
            As[seg * 4 + 3][row] = a4.w;
        }
        {   // B tile 16x128
            int kk = t >> 4, nn = (t & 15) * 8;
            float4 b0 = *(const float4*)(&Bmat[(size_t)(k0 + kk) * 1024 + n0 + nn]);
            float4 b1 = *(const float4*)(&Bmat[(size_t)(k0 + kk) * 1024 + n0 + nn + 4]);
            *(float4*)&Bs[kk][nn]     = b0;
            *(float4*)&Bs[kk][nn + 4] = b1;
        }
        __syncthreads();
        #pragma unroll
        for (int k = 0; k < BK; ++k) {
            float4 a  = *(const float4*)&As[k][tm];
            float4 b0 = *(const float4*)&Bs[k][tn];
            float4 b1 = *(const float4*)&Bs[k][tn + 4];
            float av[4] = {a.x, a.y, a.z, a.w};
            float bv[8] = {b0.x, b0.y, b0.z, b0.w, b1.x, b1.y, b1.z, b1.w};
            #pragma unroll
            for (int i = 0; i < 4; ++i)
                #pragma unroll
                for (int j = 0; j < 8; ++j)
                    acc[i][j] += av[i] * bv[j];
        }
        __syncthreads();
    }
    #pragma unroll
    for (int i = 0; i < 4; ++i) {
        int m = m0 + tm + i;
        #pragma unroll
        for (int j = 0; j < 8; j += 4) {
            float4 o;
            o.x = acc[i][j + 0] + bP[dir * 1024 + n0 + tn + j + 0];
            o.y = acc[i][j + 1] + bP[dir * 1024 + n0 + tn + j + 1];
            o.z = acc[i][j + 2] + bP[dir * 1024 + n0 + tn + j + 2];
            o.w = acc[i][j + 3] + bP[dir * 1024 + n0 + tn + j + 3];
            *(float4*)&C[(size_t)m * 1024 + n0 + tn + j] = o;
        }
    }
}

// ---------------------------------------------------------------------------
// LSTM recurrence. 128 teams = dir(2) x batch(64); 4 WGs/team (us slice of 64
// units); grid 512 blocks x 512 threads, 2 teams/CU.
//   thread t: u_loc = t>>3 (unit), ks = t&7 (32-k slice).
//   Weights (128 VGPR) + emission wl (32 VGPR) pinned register-resident via
//   asm barriers. No LDS: h(s-1) loaded global->reg (8-lane groups share the
//   same slice), gates + fused emission reduced by intra-group shfl.
//   One __syncthreads per step; each wave self-gates on peer flags with
//   acquire loads (also invalidates L1 for the parity-slot re-read).
// ---------------------------------------------------------------------------
__global__ __launch_bounds__(512, 4) void lstm_team_kernel(
    const int* __restrict__ sentence,
    const float* __restrict__ embproj,
    const float* __restrict__ Whh4,
    const float* __restrict__ WlinT,
    float* __restrict__ h_glob,
    int* __restrict__ flags,
    float* __restrict__ emis_f,
    float* __restrict__ emis_b)
{
    const int bx   = blockIdx.x;
    const int xcd  = bx & 7, slot = bx >> 3;
    const int team = xcd * 16 + (slot & 15);   // 0..127 (4 members same XCD)
    const int us   = slot >> 4;                // 0..3
    const int dir  = team >> 6;
    const int b    = team & 63;
    const int u0   = us * 64;
    const int t    = threadIdx.x;
    const int u_loc = t >> 3;     // 0..63
    const int ks    = t & 7;      // 0..7
    const int lane  = t & 63;

    // ---- persistent weights -> pinned VGPRs ----
    float4 w4[32];
    {
        const float* Wb = Whh4 + (size_t)dir * WMAT_PER_DIR
                        + (size_t)(ks * 32) * 1024 + (size_t)(u0 + u_loc) * 4;
        #pragma unroll
        for (int kk = 0; kk < 32; ++kk)
            w4[kk] = *(const float4*)(Wb + (size_t)kk * 1024);
    }
    #pragma unroll
    for (int kk = 0; kk < 32; ++kk)
        asm volatile("" : "+v"(w4[kk].x), "+v"(w4[kk].y), "+v"(w4[kk].z), "+v"(w4[kk].w));

    float4 wlv[8];
    {
        const float* WlB = WlinT + dir * 1024 + us * 256 + ks * 32;
        #pragma unroll
        for (int kk = 0; kk < 8; ++kk)
            wlv[kk] = *(const float4*)(WlB + kk * 4);
    }
    #pragma unroll
    for (int kk = 0; kk < 8; ++kk)
        asm volatile("" : "+v"(wlv[kk].x), "+v"(wlv[kk].y), "+v"(wlv[kk].z), "+v"(wlv[kk].w));

    const bool is_act = (ks == 0);
    const int fl_base = team * 4;
    float* Hbase = h_glob + (size_t)team * 512;   // [parity][256]
    const float* EP = embproj + (size_t)dir * EPROJ_PER_DIR;
    float* emis = dir ? emis_b : emis_f;
    const int* sent = sentence + (size_t)b * Ss;

    float c = 0.f;
    long budget = 50000000;   // bounded spin: wrong answer instead of hang on bug

    for (int s = 0; s < Ss; ++s) {
        const int pos = dir ? (Ss - 1 - s) : s;
        float4 ep;
        if (is_act) {   // prefetch gate preactivation row (L3-resident table)
            const int tok = sent[pos];
            ep = *(const float4*)(EP + (size_t)tok * 1024 + (u0 + u_loc) * 4);
        }

        float4 acc = make_float4(0.f, 0.f, 0.f, 0.f);
        float em = 0.f;
        if (s > 0) {
            // every wave self-gates: 3 lanes poll the 3 peer flags (acquire)
            if (lane < 3) {
                const int peer = fl_base + ((us + 1 + lane) & 3);
                while (__hip_atomic_load(&flags[peer], __ATOMIC_ACQUIRE,
                                         __HIP_MEMORY_SCOPE_AGENT) < s) {
                    if (--budget < 0) break;
                }
            }
            // h(s-1) slice -> registers (8-lane group reads identical slice)
            const float* hsrc = Hbase + ((s - 1) & 1) * 256 + ks * 32;
            float4 hv[8];
            #pragma unroll
            for (int kk = 0; kk < 8; ++kk) hv[kk] = *(const float4*)(hsrc + kk * 4);

            #pragma unroll
            for (int kk = 0; kk < 8; ++kk) {
                const float4 h4 = hv[kk];
                const float4 wA = w4[kk*4+0], wB2 = w4[kk*4+1],
                             wC = w4[kk*4+2], wD = w4[kk*4+3];
                acc.x += h4.x*wA.x;  acc.y += h4.x*wA.y;  acc.z += h4.x*wA.z;  acc.w += h4.x*wA.w;
                acc.x += h4.y*wB2.x; acc.y += h4.y*wB2.y; acc.z += h4.y*wB2.z; acc.w += h4.y*wB2.w;
                acc.x += h4.z*wC.x;  acc.y += h4.z*wC.y;  acc.z += h4.z*wC.z;  acc.w += h4.z*wC.w;
                acc.x += h4.w*wD.x;  acc.y += h4.w*wD.y;  acc.z += h4.w*wD.z;  acc.w += h4.w*wD.w;
            }
            if (t < 64) {   // fused emission for step s-1 (tag us), wave 0 only
                #pragma unroll
                for (int kk = 0; kk < 8; ++kk)
                    em += hv[kk].x*wlv[kk].x + hv[kk].y*wlv[kk].y
                        + hv[kk].z*wlv[kk].z + hv[kk].w*wlv[kk].w;
            }
            #pragma unroll
            for (int off = 4; off > 0; off >>= 1) {
                acc.x += __shfl_down(acc.x, off); acc.y += __shfl_down(acc.y, off);
                acc.z += __shfl_down(acc.z, off); acc.w += __shfl_down(acc.w, off);
                em    += __shfl_down(em, off);
            }
            if (t == 0) {
                const int pm1 = dir ? (Ss - s) : (s - 1);
                emis[((size_t)pm1 * Bb + b) * 4 + us] = em;
            }
        }

        if (is_act) {
            const float gi = acc.x + ep.x, gf = acc.y + ep.y,
                        gg = acc.z + ep.z, go = acc.w + ep.w;
            c = sigm(gf) * c + sigm(gi) * tanhf(gg);
            const float hval = sigm(go) * tanhf(c);
            Hbase[(s & 1) * 256 + u0 + u_loc] = hval;
        }
        __syncthreads();   // drains all waves' h stores (per-wave vmcnt0)
        if (t == 0)
            __hip_atomic_store(&flags[fl_base + us], s + 1, __ATOMIC_RELEASE,
                               __HIP_MEMORY_SCOPE_AGENT);
    }

    // epilogue: emission for h(Ss-1)
    if (lane < 3) {
        const int peer = fl_base + ((us + 1 + lane) & 3);
        while (__hip_atomic_load(&flags[peer], __ATOMIC_ACQUIRE,
                                 __HIP_MEMORY_SCOPE_AGENT) < Ss) {
            if (--budget < 0) break;
        }
    }
    if (t < 64) {
        const float* hsrc = Hbase + ((Ss - 1) & 1) * 256 + ks * 32;
        float em = 0.f;
        #pragma unroll
        for (int kk = 0; kk < 8; ++kk) {
            const float4 h4 = *(const float4*)(hsrc + kk * 4);
            em += h4.x*wlv[kk].x + h4.y*wlv[kk].y + h4.z*wlv[kk].z + h4.w*wlv[kk].w;
        }
        #pragma unroll
        for (int off = 4; off > 0; off >>= 1) em += __shfl_down(em, off);
        if (t == 0) {
            const int pm1 = dir ? 0 : (Ss - 1);
            emis[((size_t)pm1 * Bb + b) * 4 + us] = em;
        }
    }
}

// ---------------------------------------------------------------------------
// Fused CRF + Viterbi tail. grid 8 x 64 threads.
//   blocks 0-3: Viterbi for 16 batches each, thread = (b_loc, tag j), bp in LDS.
//   blocks 4-7: CRF llh for 16 batches each: lse scan lane-parallel over tags,
//               tag-score (num) parallel over 4 s-chunks, loss via atomicAdd.
// ---------------------------------------------------------------------------
__global__ __launch_bounds__(64) void tail_kernel(
    const float* __restrict__ emis_f, const float* __restrict__ emis_b,
    const float* __restrict__ blin, const float* __restrict__ start_t,
    const float* __restrict__ end_t, const float* __restrict__ trans,
    const int* __restrict__ tags, float* __restrict__ out_tags,
    float* __restrict__ out_loss)
{
    const int blk = blockIdx.x;
    const int t = threadIdx.x;
    const int b_loc = t >> 2, j = t & 3;
    const int base = t & ~3;

    if (blk < 4) {
        __shared__ unsigned char bp_sh[16][513][4];   // +1 row pad: bank spread
        __shared__ unsigned char tag_sh[16][520];
        const int b = blk * 16 + b_loc;
        const float trj0 = trans[0*4+j], trj1 = trans[1*4+j],
                    trj2 = trans[2*4+j], trj3 = trans[3*4+j];
        const float blj = blin[j];
        float score = start_t[j] + emis_f[(size_t)b*4 + j] + emis_b[(size_t)b*4 + j] + blj;
        for (int s = 1; s < Ss; ++s) {
            const float e = emis_f[((size_t)s*Bb + b)*4 + j]
                          + emis_b[((size_t)s*Bb + b)*4 + j] + blj;
            const float s0 = __shfl(score, base+0), s1 = __shfl(score, base+1),
                        s2 = __shfl(score, base+2), s3 = __shfl(score, base+3);
            float best = s0 + trj0; int bi = 0;
            float v = s1 + trj1; if (v > best) { best = v; bi = 1; }
            v = s2 + trj2; if (v > best) { best = v; bi = 2; }
            v = s3 + trj3; if (v > best) { best = v; bi = 3; }
            score = best + e;
            bp_sh[b_loc][s][j] = (unsigned char)bi;
        }
        const float fv = score + end_t[j];
        const float f0 = __shfl(fv, base+0), f1 = __shfl(fv, base+1),
                    f2 = __shfl(fv, base+2), f3 = __shfl(fv, base+3);
        __syncthreads();
        if (j == 0) {   // backtrack (first-occurrence argmax ties, like jnp)
            float best = f0; int tag = 0;
            if (f1 > best) { best = f1; tag = 1; }
            if (f2 > best) { best = f2; tag = 2; }
            if (f3 > best) { best = f3; tag = 3; }
            tag_sh[b_loc][Ss-1] = (unsigned char)tag;
            for (int s = Ss - 1; s >= 1; --s) {
                tag = bp_sh[b_loc][s][tag];
                tag_sh[b_loc][s-1] = (unsigned char)tag;
            }
        }
        __syncthreads();
        for (int idx = t; idx < 16 * Ss; idx += 64) {
            const int bl = idx >> 9, s = idx & (Ss - 1);
            out_tags[(size_t)(blk*16 + bl) * Ss + s] = (float)tag_sh[bl][s];
        }
    } else {
        const int b = (blk - 4) * 16 + b_loc;
        const float trj0 = trans[0*4+j], trj1 = trans[1*4+j],
                    trj2 = trans[2*4+j], trj3 = trans[3*4+j];
        const float blj = blin[j];
        float alpha = start_t[j] + emis_f[(size_t)b*4 + j] + emis_b[(size_t)b*4 + j] + blj;
        for (int s = 1; s < Ss; ++s) {
            const float e = emis_f[((size_t)s*Bb + b)*4 + j]
                          + emis_b[((size_t)s*Bb + b)*4 + j] + blj;
            const float a0 = __shfl(alpha, base+0), a1 = __shfl(alpha, base+1),
                        a2 = __shfl(alpha, base+2), a3 = __shfl(alpha, base+3);
            const float x0 = a0 + trj0, x1 = a1 + trj1, x2 = a2 + trj2, x3 = a3 + trj3;
            const float m = fmaxf(fmaxf(x0, x1), fmaxf(x2, x3));
            alpha = m + logf(expf(x0-m) + expf(x1-m) + expf(x2-m) + expf(x3-m)) + e;
        }
        const float dv = alpha + end_t[j];
        const float d0 = __shfl(dv, base+0), d1 = __shfl(dv, base+1),
                    d2 = __shfl(dv, base+2), d3 = __shfl(dv, base+3);
        const float dm = fmaxf(fmaxf(d0, d1), fmaxf(d2, d3));
        const float denom = dm + logf(expf(d0-dm) + expf(d1-dm) + expf(d2-dm) + expf(d3-dm));

        // tag-path score: thread j sums s in [j*128, j*128+128)
        const int lo = j * 128, hi = lo + 128;
        float num = 0.f;
        int tprev = (lo > 0) ? tags[(size_t)b*Ss + lo - 1] : 0;
        if (j == 0) num += start_t[tags[(size_t)b*Ss]];
        if (j == 3) num += end_t[tags[(size_t)b*Ss + Ss - 1]];
        #pragma unroll 4
        for (int s = lo; s < hi; ++s) {
            const int tg = tags[(size_t)b*Ss + s];
            num += emis_f[((size_t)s*Bb + b)*4 + tg]
                 + emis_b[((size_t)s*Bb + b)*4 + tg] + blin[tg];
            if (s > 0) num += trans[tprev*4 + tg];
            tprev = tg;
        }
        num += __shfl_xor(num, 1);
        num += __shfl_xor(num, 2);
        float lb = (j == 0) ? (denom - num) : 0.f;
        #pragma unroll
        for (int off = 32; off > 0; off >>= 1) lb += __shfl_down(lb, off);
        if (t == 0) atomicAdd(out_loss, lb);
    }
}

// ---------------------------------------------------------------------------
extern "C" void kernel_launch(void* const* d_in, const int* in_sizes, int n_in,
                              void* d_out, int out_size, void* d_ws, size_t ws_size,
                              hipStream_t stream)
{
    const int*   sentence = (const int*)d_in[0];
    const int*   tags     = (const int*)d_in[1];
    const float* emb      = (const float*)d_in[3];
    const float* Wih_f    = (const float*)d_in[4];
    const float* Whh_f    = (const float*)d_in[5];
    const float* b_f      = (const float*)d_in[6];
    const float* Wih_b    = (const float*)d_in[7];
    const float* Whh_b    = (const float*)d_in[8];
    const float* b_b      = (const float*)d_in[9];
    const float* Wlin     = (const float*)d_in[10];
    const float* blin     = (const float*)d_in[11];
    const float* start_t  = (const float*)d_in[12];
    const float* end_t    = (const float*)d_in[13];
    const float* trans    = (const float*)d_in[14];

    // workspace layout (floats)
    float* embproj = (float*)d_ws;                        // 2 * 8,192,000
    float* WihP    = embproj + 2 * EPROJ_PER_DIR;         // 2 * 262,144 (reused below)
    float* Whh4    = WihP + 2 * WMAT_PER_DIR;             // 2 * 262,144
    float* bP      = Whh4 + 2 * WMAT_PER_DIR;             // 2 * 1024
    float* WlinT   = bP + 2 * 1024;                       // 2 * 1024
    float* emis_f  = WlinT + 2 * 1024;                    // 512*64*4
    float* emis_b  = emis_f + Ss * Bb * 4;                // 512*64*4

    // WihP region is dead after the GEMM -> reuse for sync flags + h exchange
    int*   flags  = (int*)WihP;                           // 512 ints
    float* h_glob = WihP + 1024;                          // 128 teams * 512 floats

    prep_kernel<<<2048, 256, 0, stream>>>(Wih_f, Whh_f, b_f, Wih_b, Whh_b, b_b, Wlin,
                                          WihP, Whh4, bP, WlinT);
    dim3 gg(Vv / BM, 1024 / BN, 2);
    embproj_gemm<<<gg, 256, 0, stream>>>(emb, WihP, bP, embproj);

    hipMemsetAsync(flags, 0, 512 * sizeof(int), stream);

    const int* k_sent = sentence;
    const float* k_ep = embproj;
    const float* k_whh = Whh4;
    const float* k_wlin = WlinT;
    float* k_h = h_glob;
    int* k_fl = flags;
    float* k_ef = emis_f;
    float* k_eb = emis_b;
    void* args[] = { (void*)&k_sent, (void*)&k_ep, (void*)&k_whh, (void*)&k_wlin,
                     (void*)&k_h, (void*)&k_fl, (void*)&k_ef, (void*)&k_eb };
    hipLaunchCooperativeKernel((const void*)lstm_team_kernel, dim3(512), dim3(512),
                               args, 0, stream);

    float* out = (float*)d_out;
    float* out_loss = out + Bb * Ss;
    hipMemsetAsync(out_loss, 0, sizeof(float), stream);
    tail_kernel<<<8, 64, 0, stream>>>(emis_f, emis_b, blin, start_t, end_t, trans,
                                      tags, out, out_loss);
}

// Round 4
// 17466.885 us; speedup vs baseline: 2.4823x; 2.4823x over previous
//
#include <hip/hip_runtime.h>
#include <math.h>

// Problem constants
#define Vv 8000
#define Ee 256
#define Hh 256
#define Tt 4
#define Bb 64
#define Ss 512

#define EPROJ_PER_DIR (Vv * 1024)   // 8,192,000 floats per direction
#define WMAT_PER_DIR  (Ee * 1024)   // 262,144 floats per direction

__device__ __forceinline__ float sigm(float x) { return 1.f / (1.f + expf(-x)); }

// ---------------------------------------------------------------------------
// prep: repack weights.
//   WihP [dir][e][j']  j' = u*4+g  <-> gate-row g*256+u   (GEMM B-matrix)
//   Whh4 [dir][k][u*4+g] = Whh[g*256+u][k]                (recurrent)
//   bP   [dir][j']     = b[g*256+u]
//   WlinT[dir][t][u]   = Wlin[t][dir*256+u]               (emission, transposed)
// ---------------------------------------------------------------------------
__global__ void prep_kernel(const float* __restrict__ Wih_f, const float* __restrict__ Whh_f,
                            const float* __restrict__ b_f,
                            const float* __restrict__ Wih_b, const float* __restrict__ Whh_b,
                            const float* __restrict__ b_b,
                            const float* __restrict__ Wlin,
                            float* __restrict__ WihP, float* __restrict__ Whh4,
                            float* __restrict__ bP, float* __restrict__ WlinT)
{
    int tid = blockIdx.x * blockDim.x + threadIdx.x;   // [0, 2*262144)
    int dir = tid >> 18;
    int r   = tid & 262143;
    int k   = r >> 10;        // 0..255 (e or k)
    int jp  = r & 1023;       // j'
    int u   = jp >> 2;
    int g   = jp & 3;
    int row = g * 256 + u;    // original gate row
    const float* Wih = dir ? Wih_b : Wih_f;
    const float* Whh = dir ? Whh_b : Whh_f;
    const float* bv  = dir ? b_b   : b_f;
    WihP[dir * WMAT_PER_DIR + k * 1024 + jp] = Wih[row * 256 + k];
    Whh4[dir * WMAT_PER_DIR + k * 1024 + jp] = Whh[row * 256 + k];
    if (r < 1024) {
        bP[dir * 1024 + jp] = bv[row];
        int uu = r >> 2, tt = r & 3;
        WlinT[dir * 1024 + tt * 256 + uu] = Wlin[tt * (2 * Hh) + dir * 256 + uu];
    }
}

// ---------------------------------------------------------------------------
// embproj GEMM: embproj[dir][v][j'] = sum_e emb[v][e]*WihP[dir][e][j'] + bP[dir][j']
// ---------------------------------------------------------------------------
#define BM 64
#define BN 128
#define BK 16
__global__ __launch_bounds__(256) void embproj_gemm(const float* __restrict__ emb,
                                                    const float* __restrict__ WihP,
                                                    const float* __restrict__ bP,
                                                    float* __restrict__ embproj)
{
    int dir = blockIdx.z;
    const float* Bmat = WihP + dir * WMAT_PER_DIR;
    float* C = embproj + (size_t)dir * EPROJ_PER_DIR;
    int m0 = blockIdx.x * BM;
    int n0 = blockIdx.y * BN;

    __shared__ float As[BK][BM];
    __shared__ float Bs[BK][BN];

    int t = threadIdx.x;
    int tm = (t & 15) * 4;
    int tn = (t >> 4) * 8;
    float acc[4][8];
    #pragma unroll
    for (int i = 0; i < 4; ++i)
        #pragma unroll
        for (int j = 0; j < 8; ++j) acc[i][j] = 0.f;

    for (int k0 = 0; k0 < Ee; k0 += BK) {
        {   // A tile 64x16
            int row = t >> 2, seg = t & 3;
            float4 a4 = *(const float4*)(&emb[(size_t)(m0 + row) * Ee + k0 + seg * 4]);
            As[seg * 4 + 0][row] = a4.x;
            As[seg * 4 + 1][row] = a4.y;
            As[seg * 4 + 2][row] = a4.z;
            As[seg * 4 + 3][row] = a4.w;
        }
        {   // B tile 16x128
            int kk = t >> 4, nn = (t & 15) * 8;
            float4 b0 = *(const float4*)(&Bmat[(size_t)(k0 + kk) * 1024 + n0 + nn]);
            float4 b1 = *(const float4*)(&Bmat[(size_t)(k0 + kk) * 1024 + n0 + nn + 4]);
            *(float4*)&Bs[kk][nn]     = b0;
            *(float4*)&Bs[kk][nn + 4] = b1;
        }
        __syncthreads();
        #pragma unroll
        for (int k = 0; k < BK; ++k) {
            float4 a  = *(const float4*)&As[k][tm];
            float4 b0 = *(const float4*)&Bs[k][tn];
            float4 b1 = *(const float4*)&Bs[k][tn + 4];
            float av[4] = {a.x, a.y, a.z, a.w};
            float bv[8] = {b0.x, b0.y, b0.z, b0.w, b1.x, b1.y, b1.z, b1.w};
            #pragma unroll
            for (int i = 0; i < 4; ++i)
                #pragma unroll
                for (int j = 0; j < 8; ++j)
                    acc[i][j] += av[i] * bv[j];
        }
        __syncthreads();
    }
    #pragma unroll
    for (int i = 0; i < 4; ++i) {
        int m = m0 + tm + i;
        #pragma unroll
        for (int j = 0; j < 8; j += 4) {
            float4 o;
            o.x = acc[i][j + 0] + bP[dir * 1024 + n0 + tn + j + 0];
            o.y = acc[i][j + 1] + bP[dir * 1024 + n0 + tn + j + 1];
            o.z = acc[i][j + 2] + bP[dir * 1024 + n0 + tn + j + 2];
            o.w = acc[i][j + 3] + bP[dir * 1024 + n0 + tn + j + 3];
            *(float4*)&C[(size_t)m * 1024 + n0 + tn + j] = o;
        }
    }
}

// ---------------------------------------------------------------------------
// LSTM recurrence. 64 teams = dir(2) x batch-pair(32); 4 WGs/team (us = slice
// of 64 hidden units). grid 256 x 512, 1 block/CU, cooperative.
//   thread t: u_loc = t>>3 (unit), ks = t&7 (32-k slice).
//   Whh slice (128 VGPR) pinned register-resident via asm barriers;
//   __launch_bounds__(512,2) -> 256-VGPR cap so the pin CAN hold (R3 bug:
//   (512,4) capped at 128 and forced a 24.7 GB scratch-spill catastrophe).
//   No LDS: h(s-1) read global->reg (8-lane groups share a slice); gate and
//   fused-emission sums reduced by intra-group shfl. One __syncthreads/step;
//   waves self-gate on peer flags with acquire loads (team members share an
//   XCD via the bx&7 swizzle, so release/acquire through the common L2).
// ---------------------------------------------------------------------------
__global__ __launch_bounds__(512, 2) void lstm_team_kernel(
    const int* __restrict__ sentence,
    const float* __restrict__ embproj,
    const float* __restrict__ Whh4,
    const float* __restrict__ WlinT,
    float* __restrict__ h_glob,
    int* __restrict__ flags,
    float* __restrict__ emis_f,
    float* __restrict__ emis_b)
{
    const int bx   = blockIdx.x;
    const int xcd  = bx & 7, slot = bx >> 3;       // slot 0..31
    const int team = xcd * 8 + (slot & 7);         // 0..63 (members same XCD)
    const int us   = slot >> 3;                    // 0..3
    const int dir  = team >> 5;
    const int bg   = team & 31;
    const int b0   = bg * 2;
    const int u0   = us * 64;
    const int t    = threadIdx.x;
    const int u_loc = t >> 3;     // 0..63
    const int ks    = t & 7;      // 0..7
    const int lane  = t & 63;

    // ---- persistent Whh slice -> pinned VGPRs (128) ----
    float4 w4[32];
    {
        const float* Wb = Whh4 + (size_t)dir * WMAT_PER_DIR
                        + (size_t)(ks * 32) * 1024 + (size_t)(u0 + u_loc) * 4;
        #pragma unroll
        for (int kk = 0; kk < 32; ++kk)
            w4[kk] = *(const float4*)(Wb + (size_t)kk * 1024);
    }
    #pragma unroll
    for (int kk = 0; kk < 32; ++kk)
        asm volatile("" : "+v"(w4[kk].x), "+v"(w4[kk].y), "+v"(w4[kk].z), "+v"(w4[kk].w));

    const bool is_act = (ks == 0);
    const int fl_base = team * 4;
    float* Hbase = h_glob + (size_t)team * 1024;   // [parity][2 batches][256]
    const float* EP = embproj + (size_t)dir * EPROJ_PER_DIR;
    const float* WlB = WlinT + dir * 1024 + us * 256 + ks * 32;  // 1KB, L1-hot
    float* emis = dir ? emis_b : emis_f;
    const int* sentA = sentence + (size_t)b0 * Ss;
    const int* sentB = sentence + (size_t)(b0 + 1) * Ss;

    float cA = 0.f, cB = 0.f;
    long budget = 50000000;   // bounded spin: wrong answer instead of hang on bug

    for (int s = 0; s < Ss; ++s) {
        const int pos = dir ? (Ss - 1 - s) : s;
        float4 epA, epB;
        if (is_act) {   // prefetch gate preactivation rows (L3-resident table)
            const int tokA = sentA[pos];
            const int tokB = sentB[pos];
            epA = *(const float4*)(EP + (size_t)tokA * 1024 + (u0 + u_loc) * 4);
            epB = *(const float4*)(EP + (size_t)tokB * 1024 + (u0 + u_loc) * 4);
        }

        float4 accA = make_float4(0.f, 0.f, 0.f, 0.f);
        float4 accB = make_float4(0.f, 0.f, 0.f, 0.f);
        float emA = 0.f, emB = 0.f;
        if (s > 0) {
            // every wave self-gates: 3 lanes poll the 3 peer flags (acquire)
            if (lane < 3) {
                const int peer = fl_base + ((us + 1 + lane) & 3);
                while (__hip_atomic_load(&flags[peer], __ATOMIC_ACQUIRE,
                                         __HIP_MEMORY_SCOPE_AGENT) < s) {
                    if (--budget < 0) break;
                }
            }
            const float* hpar = Hbase + ((s - 1) & 1) * 512;
            {   // ---- batch A ----
                const float* hsrc = hpar + ks * 32;
                float4 hv[8];
                #pragma unroll
                for (int kk = 0; kk < 8; ++kk) hv[kk] = *(const float4*)(hsrc + kk * 4);
                #pragma unroll
                for (int kk = 0; kk < 8; ++kk) {
                    const float4 h4 = hv[kk];
                    const float4 wA = w4[kk*4+0], wB2 = w4[kk*4+1],
                                 wC = w4[kk*4+2], wD = w4[kk*4+3];
                    accA.x += h4.x*wA.x;  accA.y += h4.x*wA.y;  accA.z += h4.x*wA.z;  accA.w += h4.x*wA.w;
                    accA.x += h4.y*wB2.x; accA.y += h4.y*wB2.y; accA.z += h4.y*wB2.z; accA.w += h4.y*wB2.w;
                    accA.x += h4.z*wC.x;  accA.y += h4.z*wC.y;  accA.z += h4.z*wC.z;  accA.w += h4.z*wC.w;
                    accA.x += h4.w*wD.x;  accA.y += h4.w*wD.y;  accA.z += h4.w*wD.z;  accA.w += h4.w*wD.w;
                }
                if (t < 64) {   // fused emission A (tag us), wave 0 only; wl from L1
                    #pragma unroll
                    for (int kk = 0; kk < 8; ++kk) {
                        const float4 wl = *(const float4*)(WlB + kk * 4);
                        emA += hv[kk].x*wl.x + hv[kk].y*wl.y + hv[kk].z*wl.z + hv[kk].w*wl.w;
                    }
                }
            }
            {   // ---- batch B ----
                const float* hsrc = hpar + 256 + ks * 32;
                float4 hv[8];
                #pragma unroll
                for (int kk = 0; kk < 8; ++kk) hv[kk] = *(const float4*)(hsrc + kk * 4);
                #pragma unroll
                for (int kk = 0; kk < 8; ++kk) {
                    const float4 h4 = hv[kk];
                    const float4 wA = w4[kk*4+0], wB2 = w4[kk*4+1],
                                 wC = w4[kk*4+2], wD = w4[kk*4+3];
                    accB.x += h4.x*wA.x;  accB.y += h4.x*wA.y;  accB.z += h4.x*wA.z;  accB.w += h4.x*wA.w;
                    accB.x += h4.y*wB2.x; accB.y += h4.y*wB2.y; accB.z += h4.y*wB2.z; accB.w += h4.y*wB2.w;
                    accB.x += h4.z*wC.x;  accB.y += h4.z*wC.y;  accB.z += h4.z*wC.z;  accB.w += h4.z*wC.w;
                    accB.x += h4.w*wD.x;  accB.y += h4.w*wD.y;  accB.z += h4.w*wD.z;  accB.w += h4.w*wD.w;
                }
                if (t >= 64 && t < 128) {   // fused emission B, wave 1 only
                    #pragma unroll
                    for (int kk = 0; kk < 8; ++kk) {
                        const float4 wl = *(const float4*)(WlB + kk * 4);
                        emB += hv[kk].x*wl.x + hv[kk].y*wl.y + hv[kk].z*wl.z + hv[kk].w*wl.w;
                    }
                }
            }
            #pragma unroll
            for (int off = 4; off > 0; off >>= 1) {
                accA.x += __shfl_down(accA.x, off); accA.y += __shfl_down(accA.y, off);
                accA.z += __shfl_down(accA.z, off); accA.w += __shfl_down(accA.w, off);
                accB.x += __shfl_down(accB.x, off); accB.y += __shfl_down(accB.y, off);
                accB.z += __shfl_down(accB.z, off); accB.w += __shfl_down(accB.w, off);
                emA += __shfl_down(emA, off);
                emB += __shfl_down(emB, off);
            }
            const int pm1 = dir ? (Ss - s) : (s - 1);
            if (t == 0)
                emis[((size_t)pm1 * Bb + b0) * 4 + us] = emA;
            if (t == 64)
                emis[((size_t)pm1 * Bb + b0 + 1) * 4 + us] = emB;
        }

        if (is_act) {
            float* dst = Hbase + (s & 1) * 512;
            {
                const float gi = accA.x + epA.x, gf = accA.y + epA.y,
                            gg = accA.z + epA.z, go = accA.w + epA.w;
                cA = sigm(gf) * cA + sigm(gi) * tanhf(gg);
                dst[u0 + u_loc] = sigm(go) * tanhf(cA);
            }
            {
                const float gi = accB.x + epB.x, gf = accB.y + epB.y,
                            gg = accB.z + epB.z, go = accB.w + epB.w;
                cB = sigm(gf) * cB + sigm(gi) * tanhf(gg);
                dst[256 + u0 + u_loc] = sigm(go) * tanhf(cB);
            }
        }
        __syncthreads();   // each wave drains its own h stores (vmcnt) at barrier
        if (t == 0)
            __hip_atomic_store(&flags[fl_base + us], s + 1, __ATOMIC_RELEASE,
                               __HIP_MEMORY_SCOPE_AGENT);
    }

    // epilogue: emission for the last h
    if (lane < 3) {
        const int peer = fl_base + ((us + 1 + lane) & 3);
        while (__hip_atomic_load(&flags[peer], __ATOMIC_ACQUIRE,
                                 __HIP_MEMORY_SCOPE_AGENT) < Ss) {
            if (--budget < 0) break;
        }
    }
    if (t < 128) {
        const int batch = t >> 6;                  // wave0 -> A, wave1 -> B
        const float* hsrc = Hbase + ((Ss - 1) & 1) * 512 + batch * 256 + ks * 32;
        float em = 0.f;
        #pragma unroll
        for (int kk = 0; kk < 8; ++kk) {
            const float4 h4 = *(const float4*)(hsrc + kk * 4);
            const float4 wl = *(const float4*)(WlB + kk * 4);
            em += h4.x*wl.x + h4.y*wl.y + h4.z*wl.z + h4.w*wl.w;
        }
        #pragma unroll
        for (int off = 4; off > 0; off >>= 1) em += __shfl_down(em, off);
        if ((t & 63) == 0) {
            const int pm1 = dir ? 0 : (Ss - 1);
            emis[((size_t)pm1 * Bb + b0 + batch) * 4 + us] = em;
        }
    }
}

// ---------------------------------------------------------------------------
// Fused CRF + Viterbi tail. grid 8 x 64 threads.
//   blocks 0-3: Viterbi for 16 batches each, thread = (b_loc, tag j), bp in LDS.
//   blocks 4-7: CRF llh for 16 batches each: lse scan lane-parallel over tags,
//               tag-score (num) parallel over 4 s-chunks, loss via atomicAdd.
// ---------------------------------------------------------------------------
__global__ __launch_bounds__(64) void tail_kernel(
    const float* __restrict__ emis_f, const float* __restrict__ emis_b,
    const float* __restrict__ blin, const float* __restrict__ start_t,
    const float* __restrict__ end_t, const float* __restrict__ trans,
    const int* __restrict__ tags, float* __restrict__ out_tags,
    float* __restrict__ out_loss)
{
    const int blk = blockIdx.x;
    const int t = threadIdx.x;
    const int b_loc = t >> 2, j = t & 3;
    const int base = t & ~3;

    if (blk < 4) {
        __shared__ unsigned char bp_sh[16][513][4];   // +1 row pad: bank spread
        __shared__ unsigned char tag_sh[16][520];
        const int b = blk * 16 + b_loc;
        const float trj0 = trans[0*4+j], trj1 = trans[1*4+j],
                    trj2 = trans[2*4+j], trj3 = trans[3*4+j];
        const float blj = blin[j];
        float score = start_t[j] + emis_f[(size_t)b*4 + j] + emis_b[(size_t)b*4 + j] + blj;
        for (int s = 1; s < Ss; ++s) {
            const float e = emis_f[((size_t)s*Bb + b)*4 + j]
                          + emis_b[((size_t)s*Bb + b)*4 + j] + blj;
            const float s0 = __shfl(score, base+0), s1 = __shfl(score, base+1),
                        s2 = __shfl(score, base+2), s3 = __shfl(score, base+3);
            float best = s0 + trj0; int bi = 0;
            float v = s1 + trj1; if (v > best) { best = v; bi = 1; }
            v = s2 + trj2; if (v > best) { best = v; bi = 2; }
            v = s3 + trj3; if (v > best) { best = v; bi = 3; }
            score = best + e;
            bp_sh[b_loc][s][j] = (unsigned char)bi;
        }
        const float fv = score + end_t[j];
        const float f0 = __shfl(fv, base+0), f1 = __shfl(fv, base+1),
                    f2 = __shfl(fv, base+2), f3 = __shfl(fv, base+3);
        __syncthreads();
        if (j == 0) {   // backtrack (first-occurrence argmax ties, like jnp)
            float best = f0; int tag = 0;
            if (f1 > best) { best = f1; tag = 1; }
            if (f2 > best) { best = f2; tag = 2; }
            if (f3 > best) { best = f3; tag = 3; }
            tag_sh[b_loc][Ss-1] = (unsigned char)tag;
            for (int s = Ss - 1; s >= 1; --s) {
                tag = bp_sh[b_loc][s][tag];
                tag_sh[b_loc][s-1] = (unsigned char)tag;
            }
        }
        __syncthreads();
        for (int idx = t; idx < 16 * Ss; idx += 64) {
            const int bl = idx >> 9, s = idx & (Ss - 1);
            out_tags[(size_t)(blk*16 + bl) * Ss + s] = (float)tag_sh[bl][s];
        }
    } else {
        const int b = (blk - 4) * 16 + b_loc;
        const float trj0 = trans[0*4+j], trj1 = trans[1*4+j],
                    trj2 = trans[2*4+j], trj3 = trans[3*4+j];
        const float blj = blin[j];
        float alpha = start_t[j] + emis_f[(size_t)b*4 + j] + emis_b[(size_t)b*4 + j] + blj;
        for (int s = 1; s < Ss; ++s) {
            const float e = emis_f[((size_t)s*Bb + b)*4 + j]
                          + emis_b[((size_t)s*Bb + b)*4 + j] + blj;
            const float a0 = __shfl(alpha, base+0), a1 = __shfl(alpha, base+1),
                        a2 = __shfl(alpha, base+2), a3 = __shfl(alpha, base+3);
            const float x0 = a0 + trj0, x1 = a1 + trj1, x2 = a2 + trj2, x3 = a3 + trj3;
            const float m = fmaxf(fmaxf(x0, x1), fmaxf(x2, x3));
            alpha = m + logf(expf(x0-m) + expf(x1-m) + expf(x2-m) + expf(x3-m)) + e;
        }
        const float dv = alpha + end_t[j];
        const float d0 = __shfl(dv, base+0), d1 = __shfl(dv, base+1),
                    d2 = __shfl(dv, base+2), d3 = __shfl(dv, base+3);
        const float dm = fmaxf(fmaxf(d0, d1), fmaxf(d2, d3));
        const float denom = dm + logf(expf(d0-dm) + expf(d1-dm) + expf(d2-dm) + expf(d3-dm));

        // tag-path score: thread j sums s in [j*128, j*128+128)
        const int lo = j * 128, hi = lo + 128;
        float num = 0.f;
        int tprev = (lo > 0) ? tags[(size_t)b*Ss + lo - 1] : 0;
        if (j == 0) num += start_t[tags[(size_t)b*Ss]];
        if (j == 3) num += end_t[tags[(size_t)b*Ss + Ss - 1]];
        #pragma unroll 4
        for (int s = lo; s < hi; ++s) {
            const int tg = tags[(size_t)b*Ss + s];
            num += emis_f[((size_t)s*Bb + b)*4 + tg]
                 + emis_b[((size_t)s*Bb + b)*4 + tg] + blin[tg];
            if (s > 0) num += trans[tprev*4 + tg];
            tprev = tg;
        }
        num += __shfl_xor(num, 1);
        num += __shfl_xor(num, 2);
        float lb = (j == 0) ? (denom - num) : 0.f;
        #pragma unroll
        for (int off = 32; off > 0; off >>= 1) lb += __shfl_down(lb, off);
        if (t == 0) atomicAdd(out_loss, lb);
    }
}

// ---------------------------------------------------------------------------
extern "C" void kernel_launch(void* const* d_in, const int* in_sizes, int n_in,
                              void* d_out, int out_size, void* d_ws, size_t ws_size,
                              hipStream_t stream)
{
    const int*   sentence = (const int*)d_in[0];
    const int*   tags     = (const int*)d_in[1];
    const float* emb      = (const float*)d_in[3];
    const float* Wih_f    = (const float*)d_in[4];
    const float* Whh_f    = (const float*)d_in[5];
    const float* b_f      = (const float*)d_in[6];
    const float* Wih_b    = (const float*)d_in[7];
    const float* Whh_b    = (const float*)d_in[8];
    const float* b_b      = (const float*)d_in[9];
    const float* Wlin     = (const float*)d_in[10];
    const float* blin     = (const float*)d_in[11];
    const float* start_t  = (const float*)d_in[12];
    const float* end_t    = (const float*)d_in[13];
    const float* trans    = (const float*)d_in[14];

    // workspace layout (floats)
    float* embproj = (float*)d_ws;                        // 2 * 8,192,000
    float* WihP    = embproj + 2 * EPROJ_PER_DIR;         // 2 * 262,144 (reused below)
    float* Whh4    = WihP + 2 * WMAT_PER_DIR;             // 2 * 262,144
    float* bP      = Whh4 + 2 * WMAT_PER_DIR;             // 2 * 1024
    float* WlinT   = bP + 2 * 1024;                       // 2 * 1024
    float* emis_f  = WlinT + 2 * 1024;                    // 512*64*4
    float* emis_b  = emis_f + Ss * Bb * 4;                // 512*64*4

    // WihP region is dead after the GEMM -> reuse for sync flags + h exchange
    int*   flags  = (int*)WihP;                           // 256 ints
    float* h_glob = WihP + 1024;                          // 64 teams * 1024 floats

    prep_kernel<<<2048, 256, 0, stream>>>(Wih_f, Whh_f, b_f, Wih_b, Whh_b, b_b, Wlin,
                                          WihP, Whh4, bP, WlinT);
    dim3 gg(Vv / BM, 1024 / BN, 2);
    embproj_gemm<<<gg, 256, 0, stream>>>(emb, WihP, bP, embproj);

    hipMemsetAsync(flags, 0, 512 * sizeof(int), stream);

    const int* k_sent = sentence;
    const float* k_ep = embproj;
    const float* k_whh = Whh4;
    const float* k_wlin = WlinT;
    float* k_h = h_glob;
    int* k_fl = flags;
    float* k_ef = emis_f;
    float* k_eb = emis_b;
    void* args[] = { (void*)&k_sent, (void*)&k_ep, (void*)&k_whh, (void*)&k_wlin,
                     (void*)&k_h, (void*)&k_fl, (void*)&k_ef, (void*)&k_eb };
    hipLaunchCooperativeKernel((const void*)lstm_team_kernel, dim3(256), dim3(512),
                               args, 0, stream);

    float* out = (float*)d_out;
    float* out_loss = out + Bb * Ss;
    hipMemsetAsync(out_loss, 0, sizeof(float), stream);
    tail_kernel<<<8, 64, 0, stream>>>(emis_f, emis_b, blin, start_t, end_t, trans,
                                      tags, out, out_loss);
}

// Round 5
// 6215.838 us; speedup vs baseline: 6.9753x; 2.8101x over previous
//
#include <hip/hip_runtime.h>
#include <math.h>

// Problem constants
#define Vv 8000
#define Ee 256
#define Hh 256
#define Tt 4
#define Bb 64
#define Ss 512

#define EPROJ_PER_DIR (Vv * 1024)   // 8,192,000 floats per direction
#define WMAT_PER_DIR  (Ee * 1024)   // 262,144 floats per direction

__device__ __forceinline__ float sigm(float x) { return 1.f / (1.f + expf(-x)); }

typedef _Float16 half2v __attribute__((ext_vector_type(2)));

__device__ __forceinline__ float fdot2u(unsigned int a, unsigned int b, float c) {
    half2v ha = __builtin_bit_cast(half2v, a);
    half2v hb = __builtin_bit_cast(half2v, b);
#if __has_builtin(__builtin_amdgcn_fdot2)
    return __builtin_amdgcn_fdot2(ha, hb, c, false);
#else
    return c + (float)ha[0] * (float)hb[0] + (float)ha[1] * (float)hb[1];
#endif
}

// ---------------------------------------------------------------------------
// prep: repack weights.
//   WihP [dir][e][j']   j' = u*4+g  <-> gate-row g*256+u   (GEMM B-matrix)
//   W16q [dir][kp][u][g] uint = f16x2 of Whh[g*256+u][2kp..2kp+1] (recurrent)
//   bP   [dir][j']      = b[g*256+u]
//   WlinQ[dir][u][t]    float4/u = Wlin[t][dir*256+u]      (emission)
// ---------------------------------------------------------------------------
__global__ void prep_kernel(const float* __restrict__ Wih_f, const float* __restrict__ Whh_f,
                            const float* __restrict__ b_f,
                            const float* __restrict__ Wih_b, const float* __restrict__ Whh_b,
                            const float* __restrict__ b_b,
                            const float* __restrict__ Wlin,
                            float* __restrict__ WihP, unsigned int* __restrict__ W16q,
                            float* __restrict__ bP, float* __restrict__ WlinQ)
{
    int tid = blockIdx.x * blockDim.x + threadIdx.x;   // [0, 2*262144)
    int dir = tid >> 18;
    int r   = tid & 262143;
    int k   = r >> 10;        // 0..255
    int jp  = r & 1023;       // j'
    int u   = jp >> 2;
    int g   = jp & 3;
    int row = g * 256 + u;    // original gate row
    const float* Wih = dir ? Wih_b : Wih_f;
    const float* Whh = dir ? Whh_b : Whh_f;
    const float* bv  = dir ? b_b   : b_f;
    WihP[dir * WMAT_PER_DIR + k * 1024 + jp] = Wih[row * 256 + k];
    if (!(k & 1)) {
        int kp = k >> 1;
        union { _Float16 h[2]; unsigned int u32; } pk;
        pk.h[0] = (_Float16)Whh[row * 256 + k];
        pk.h[1] = (_Float16)Whh[row * 256 + k + 1];
        W16q[((dir * 128 + kp) * 256 + u) * 4 + g] = pk.u32;
    }
    if (r < 1024) {
        bP[dir * 1024 + jp] = bv[row];
        int uu = r >> 2, tt = r & 3;
        WlinQ[(dir * 256 + uu) * 4 + tt] = Wlin[tt * (2 * Hh) + dir * 256 + uu];
    }
}

// ---------------------------------------------------------------------------
// embproj GEMM: embproj[dir][v][j'] = sum_e emb[v][e]*WihP[dir][e][j'] + bP[dir][j']
// ---------------------------------------------------------------------------
#define BM 64
#define BN 128
#define BK 16
__global__ __launch_bounds__(256) void embproj_gemm(const float* __restrict__ emb,
                                                    const float* __restrict__ WihP,
                                                    const float* __restrict__ bP,
                                                    float* __restrict__ embproj)
{
    int dir = blockIdx.z;
    const float* Bmat = WihP + dir * WMAT_PER_DIR;
    float* C = embproj + (size_t)dir * EPROJ_PER_DIR;
    int m0 = blockIdx.x * BM;
    int n0 = blockIdx.y * BN;

    __shared__ float As[BK][BM];
    __shared__ float Bs[BK][BN];

    int t = threadIdx.x;
    int tm = (t & 15) * 4;
    int tn = (t >> 4) * 8;
    float acc[4][8];
    #pragma unroll
    for (int i = 0; i < 4; ++i)
        #pragma unroll
        for (int j = 0; j < 8; ++j) acc[i][j] = 0.f;

    for (int k0 = 0; k0 < Ee; k0 += BK) {
        {   // A tile 64x16
            int row = t >> 2, seg = t & 3;
            float4 a4 = *(const float4*)(&emb[(size_t)(m0 + row) * Ee + k0 + seg * 4]);
            As[seg * 4 + 0][row] = a4.x;
            As[seg * 4 + 1][row] = a4.y;
            As[seg * 4 + 2][row] = a4.z;
            As[seg * 4 + 3][row] = a4.w;
        }
        {   // B tile 16x128
            int kk = t >> 4, nn = (t & 15) * 8;
            float4 b0 = *(const float4*)(&Bmat[(size_t)(k0 + kk) * 1024 + n0 + nn]);
            float4 b1 = *(const float4*)(&Bmat[(size_t)(k0 + kk) * 1024 + n0 + nn + 4]);
            *(float4*)&Bs[kk][nn]     = b0;
            *(float4*)&Bs[kk][nn + 4] = b1;
        }
        __syncthreads();
        #pragma unroll
        for (int k = 0; k < BK; ++k) {
            float4 a  = *(const float4*)&As[k][tm];
            float4 b0 = *(const float4*)&Bs[k][tn];
            float4 b1 = *(const float4*)&Bs[k][tn + 4];
            float av[4] = {a.x, a.y, a.z, a.w};
            float bv[8] = {b0.x, b0.y, b0.z, b0.w, b1.x, b1.y, b1.z, b1.w};
            #pragma unroll
            for (int i = 0; i < 4; ++i)
                #pragma unroll
                for (int j = 0; j < 8; ++j)
                    acc[i][j] += av[i] * bv[j];
        }
        __syncthreads();
    }
    #pragma unroll
    for (int i = 0; i < 4; ++i) {
        int m = m0 + tm + i;
        #pragma unroll
        for (int j = 0; j < 8; j += 4) {
            float4 o;
            o.x = acc[i][j + 0] + bP[dir * 1024 + n0 + tn + j + 0];
            o.y = acc[i][j + 1] + bP[dir * 1024 + n0 + tn + j + 1];
            o.z = acc[i][j + 2] + bP[dir * 1024 + n0 + tn + j + 2];
            o.w = acc[i][j + 3] + bP[dir * 1024 + n0 + tn + j + 3];
            *(float4*)&C[(size_t)m * 1024 + n0 + tn + j] = o;
        }
    }
}

// ---------------------------------------------------------------------------
// LSTM recurrence, f16-dot2. Team = (dir, batch-pair) = 2 WGs (us = j'-half of
// 128 units). grid 128 x 512. Thread: u_loc = tid&127, kq = tid>>7 (64-k slice).
// Weights: 32 uint4 = 128 VGPRs of f16x2, register-resident under a HARD
// amdgpu_waves_per_eu(2,2) cap (R3/R4 lesson: launch_bounds min-waves lets the
// allocator pick 128 and spill). K-partials reduced via LDS intra-WG.
// Cross-WG per step: 256B h-half (f16) + 2 per-wave release flags; fetched by
// waves 6/7 overlapped with the second batch's compute; A/B order staggered
// between the two WGs for slack.
// ---------------------------------------------------------------------------
struct LstmShared {
    unsigned int h16[2][2][128];   // [local batch][slot][pair]
    float part[2][4][128][4];      // [local batch][kq][u_loc][gate]
    float4 wlq[128];
    float4 emred[2][2];            // [local batch][act wave]
};

template <int FIRST>
__device__ __forceinline__ void lstm_run(
    LstmShared& sh, uint4 (&w4)[32],
    const int* __restrict__ sentF, const int* __restrict__ sentS,
    const float* __restrict__ EP, unsigned int* __restrict__ hgbuf,
    int* __restrict__ flags, float* __restrict__ emisP,
    int team, int us, int dir, int b0, int tid, int u_loc, int kq,
    int lane, int wv, int uglob)
{
    const int SECOND = 1 - FIRST;
    const int bF = b0 + FIRST, bS = b0 + SECOND;
    const int di2 = dir * 2 + us;
    const int peer = 1 - us;

    float cF = 0.f, cS = 0.f;
    float4 epF, epS;
    if (tid < 128) {
        const int p0 = dir ? (Ss - 1) : 0;
        epF = *(const float4*)(EP + (size_t)sentF[p0] * 1024 + uglob * 4);
        epS = *(const float4*)(EP + (size_t)sentS[p0] * 1024 + uglob * 4);
    }
    long budget = 100000000;   // bounded spin: wrong answer instead of hang

    __syncthreads();

    for (int s = 0; s < Ss; ++s) {
        const int rd = (s + 1) & 1, wr = s & 1;
        const int posi = dir ? (Ss - 1 - s) : s;

        // ---------------- dot(FIRST) ----------------
        {
            const unsigned int* hs = &sh.h16[FIRST][rd][kq * 32];
            unsigned int hv[32];
            #pragma unroll
            for (int r = 0; r < 8; ++r) {
                uint4 q = *(const uint4*)(hs + r * 4);
                hv[r*4] = q.x; hv[r*4+1] = q.y; hv[r*4+2] = q.z; hv[r*4+3] = q.w;
            }
            float4 acc = make_float4(0.f, 0.f, 0.f, 0.f);
            #pragma unroll
            for (int kk = 0; kk < 32; ++kk) {
                acc.x = fdot2u(hv[kk], w4[kk].x, acc.x);
                acc.y = fdot2u(hv[kk], w4[kk].y, acc.y);
                acc.z = fdot2u(hv[kk], w4[kk].z, acc.z);
                acc.w = fdot2u(hv[kk], w4[kk].w, acc.w);
            }
            *(float4*)&sh.part[FIRST][kq][u_loc][0] = acc;
        }
        __syncthreads();   // b1

        // ---------------- act(FIRST) (tid<128) ----------------
        if (tid < 128) {
            float4 p0 = *(const float4*)&sh.part[FIRST][0][u_loc][0];
            float4 p1 = *(const float4*)&sh.part[FIRST][1][u_loc][0];
            float4 p2 = *(const float4*)&sh.part[FIRST][2][u_loc][0];
            float4 p3 = *(const float4*)&sh.part[FIRST][3][u_loc][0];
            float gi = p0.x + p1.x + p2.x + p3.x + epF.x;
            float gf = p0.y + p1.y + p2.y + p3.y + epF.y;
            float gg = p0.z + p1.z + p2.z + p3.z + epF.z;
            float go = p0.w + p1.w + p2.w + p3.w + epF.w;
            cF = sigm(gf) * cF + sigm(gi) * tanhf(gg);
            float h = sigm(go) * tanhf(cF);
            float4 wl = sh.wlq[u_loc];
            float4 em = make_float4(h * wl.x, h * wl.y, h * wl.z, h * wl.w);
            #pragma unroll
            for (int off = 32; off > 0; off >>= 1) {
                em.x += __shfl_down(em.x, off); em.y += __shfl_down(em.y, off);
                em.z += __shfl_down(em.z, off); em.w += __shfl_down(em.w, off);
            }
            if (lane == 0) sh.emred[FIRST][wv] = em;
            float hn = __shfl_down(h, 1);
            if (!(u_loc & 1)) {
                union { _Float16 hh[2]; unsigned int u32; } pk;
                pk.hh[0] = (_Float16)h; pk.hh[1] = (_Float16)hn;
                int idx = us * 64 + (u_loc >> 1);
                sh.h16[FIRST][wr][idx] = pk.u32;
                hgbuf[((team * 2 + FIRST) * 2 + wr) * 128 + idx] = pk.u32;
            }
            if (lane == 0)   // per-wave release: vmcnt(0) drain covers the wave's stores
                __hip_atomic_store(&flags[((team * 2 + FIRST) * 2 + us) * 2 + wv],
                                   s + 1, __ATOMIC_RELEASE, __HIP_MEMORY_SCOPE_AGENT);
            if (s + 1 < Ss) {
                const int pn = dir ? (Ss - 2 - s) : (s + 1);
                epF = *(const float4*)(EP + (size_t)sentF[pn] * 1024 + uglob * 4);
            }
        }

        // ---------------- dot(SECOND) ----------------
        {
            const unsigned int* hs = &sh.h16[SECOND][rd][kq * 32];
            unsigned int hv[32];
            #pragma unroll
            for (int r = 0; r < 8; ++r) {
                uint4 q = *(const uint4*)(hs + r * 4);
                hv[r*4] = q.x; hv[r*4+1] = q.y; hv[r*4+2] = q.z; hv[r*4+3] = q.w;
            }
            float4 acc = make_float4(0.f, 0.f, 0.f, 0.f);
            #pragma unroll
            for (int kk = 0; kk < 32; ++kk) {
                acc.x = fdot2u(hv[kk], w4[kk].x, acc.x);
                acc.y = fdot2u(hv[kk], w4[kk].y, acc.y);
                acc.z = fdot2u(hv[kk], w4[kk].z, acc.z);
                acc.w = fdot2u(hv[kk], w4[kk].w, acc.w);
            }
            *(float4*)&sh.part[SECOND][kq][u_loc][0] = acc;
        }
        __syncthreads();   // b2

        // emis store (FIRST) + act(SECOND)
        if (tid == 0) {
            float4 e0 = sh.emred[FIRST][0], e1 = sh.emred[FIRST][1];
            float4 o = make_float4(e0.x + e1.x, e0.y + e1.y, e0.z + e1.z, e0.w + e1.w);
            *(float4*)&emisP[(((size_t)di2 * Ss + posi) * Bb + bF) * 4] = o;
        }
        if (tid < 128) {
            float4 p0 = *(const float4*)&sh.part[SECOND][0][u_loc][0];
            float4 p1 = *(const float4*)&sh.part[SECOND][1][u_loc][0];
            float4 p2 = *(const float4*)&sh.part[SECOND][2][u_loc][0];
            float4 p3 = *(const float4*)&sh.part[SECOND][3][u_loc][0];
            float gi = p0.x + p1.x + p2.x + p3.x + epS.x;
            float gf = p0.y + p1.y + p2.y + p3.y + epS.y;
            float gg = p0.z + p1.z + p2.z + p3.z + epS.z;
            float go = p0.w + p1.w + p2.w + p3.w + epS.w;
            cS = sigm(gf) * cS + sigm(gi) * tanhf(gg);
            float h = sigm(go) * tanhf(cS);
            float4 wl = sh.wlq[u_loc];
            float4 em = make_float4(h * wl.x, h * wl.y, h * wl.z, h * wl.w);
            #pragma unroll
            for (int off = 32; off > 0; off >>= 1) {
                em.x += __shfl_down(em.x, off); em.y += __shfl_down(em.y, off);
                em.z += __shfl_down(em.z, off); em.w += __shfl_down(em.w, off);
            }
            if (lane == 0) sh.emred[SECOND][wv] = em;
            float hn = __shfl_down(h, 1);
            if (!(u_loc & 1)) {
                union { _Float16 hh[2]; unsigned int u32; } pk;
                pk.hh[0] = (_Float16)h; pk.hh[1] = (_Float16)hn;
                int idx = us * 64 + (u_loc >> 1);
                sh.h16[SECOND][wr][idx] = pk.u32;
                hgbuf[((team * 2 + SECOND) * 2 + wr) * 128 + idx] = pk.u32;
            }
            if (lane == 0)
                __hip_atomic_store(&flags[((team * 2 + SECOND) * 2 + us) * 2 + wv],
                                   s + 1, __ATOMIC_RELEASE, __HIP_MEMORY_SCOPE_AGENT);
            if (s + 1 < Ss) {
                const int pn = dir ? (Ss - 2 - s) : (s + 1);
                epS = *(const float4*)(EP + (size_t)sentS[pn] * 1024 + uglob * 4);
            }
        }

        // ---------------- peer-half fetch (waves 6 & 7) ----------------
        if (s + 1 < Ss && (wv == 6 || wv == 7)) {
            const int bat = (wv == 6) ? FIRST : SECOND;
            const int* fp = &flags[((team * 2 + bat) * 2 + peer) * 2 + (lane >= 32 ? 1 : 0)];
            while (__hip_atomic_load(fp, __ATOMIC_ACQUIRE, __HIP_MEMORY_SCOPE_AGENT) <= s) {
                if (--budget < 0) break;
            }
            unsigned int hp = __hip_atomic_load(
                &hgbuf[((team * 2 + bat) * 2 + wr) * 128 + peer * 64 + lane],
                __ATOMIC_RELAXED, __HIP_MEMORY_SCOPE_AGENT);
            sh.h16[bat][wr][peer * 64 + lane] = hp;
        }
        __syncthreads();   // b3

        if (tid == 0) {
            float4 e0 = sh.emred[SECOND][0], e1 = sh.emred[SECOND][1];
            float4 o = make_float4(e0.x + e1.x, e0.y + e1.y, e0.z + e1.z, e0.w + e1.w);
            *(float4*)&emisP[(((size_t)di2 * Ss + posi) * Bb + bS) * 4] = o;
        }
    }
}

__global__ __attribute__((amdgpu_flat_work_group_size(512, 512)))
__attribute__((amdgpu_waves_per_eu(2, 2))) void lstm_pair_kernel(
    const int* __restrict__ sentence,
    const float* __restrict__ embproj,
    const unsigned int* __restrict__ W16q,
    const float* __restrict__ WlinQ,
    unsigned int* __restrict__ hgbuf,
    int* __restrict__ flags,
    float* __restrict__ emisP)
{
    const int bx   = blockIdx.x;
    const int team = bx & 63;          // blocks t and t+64 share an XCD (rr % 8)
    const int us   = bx >> 6;
    const int dir  = team >> 5;
    const int bg   = team & 31;
    const int b0   = bg * 2;
    const int tid  = threadIdx.x;
    const int u_loc = tid & 127;
    const int kq    = tid >> 7;
    const int lane  = tid & 63;
    const int wv    = tid >> 6;
    const int uglob = us * 128 + u_loc;

    __shared__ LstmShared sh;

    if (tid < 128) sh.wlq[tid] = *(const float4*)&WlinQ[(dir * 256 + uglob) * 4];
    if (tid < 256) sh.h16[tid >> 7][1][tid & 127] = 0u;   // h(-1) = 0

    // persistent f16x2 weights -> 128 VGPRs
    uint4 w4[32];
    {
        const unsigned int* Wb = W16q + ((size_t)(dir * 128 + kq * 32) * 256 + uglob) * 4;
        #pragma unroll
        for (int kk = 0; kk < 32; ++kk)
            w4[kk] = *(const uint4*)(Wb + (size_t)kk * 1024);
    }
    #pragma unroll
    for (int kk = 0; kk < 32; ++kk)
        asm volatile("" : "+v"(w4[kk].x), "+v"(w4[kk].y), "+v"(w4[kk].z), "+v"(w4[kk].w));

    const float* EP = embproj + (size_t)dir * EPROJ_PER_DIR;
    const int* sentA = sentence + (size_t)b0 * Ss;
    const int* sentB = sentence + (size_t)(b0 + 1) * Ss;

    if (us == 0)
        lstm_run<0>(sh, w4, sentA, sentB, EP, hgbuf, flags, emisP,
                    team, us, dir, b0, tid, u_loc, kq, lane, wv, uglob);
    else
        lstm_run<1>(sh, w4, sentB, sentA, EP, hgbuf, flags, emisP,
                    team, us, dir, b0, tid, u_loc, kq, lane, wv, uglob);
}

// ---------------------------------------------------------------------------
// Fused CRF + Viterbi tail. grid 8 x 64 threads. emis = sum of 4 partial
// buffers emisP[di2][s][b][4] + blin.
// ---------------------------------------------------------------------------
#define EM4(DI, S_, B_, J_) emisP[((((size_t)(DI)) * Ss + (S_)) * Bb + (B_)) * 4 + (J_)]

__global__ __launch_bounds__(64) void tail_kernel(
    const float* __restrict__ emisP,
    const float* __restrict__ blin, const float* __restrict__ start_t,
    const float* __restrict__ end_t, const float* __restrict__ trans,
    const int* __restrict__ tags, float* __restrict__ out_tags,
    float* __restrict__ out_loss)
{
    const int blk = blockIdx.x;
    const int t = threadIdx.x;
    const int b_loc = t >> 2, j = t & 3;
    const int base = t & ~3;

    if (blk < 4) {
        __shared__ unsigned char bp_sh[16][513][4];
        __shared__ unsigned char tag_sh[16][520];
        const int b = blk * 16 + b_loc;
        const float trj0 = trans[0*4+j], trj1 = trans[1*4+j],
                    trj2 = trans[2*4+j], trj3 = trans[3*4+j];
        const float blj = blin[j];
        float score = start_t[j] + blj
                    + EM4(0,0,b,j) + EM4(1,0,b,j) + EM4(2,0,b,j) + EM4(3,0,b,j);
        for (int s = 1; s < Ss; ++s) {
            const float e = EM4(0,s,b,j) + EM4(1,s,b,j) + EM4(2,s,b,j) + EM4(3,s,b,j) + blj;
            const float s0 = __shfl(score, base+0), s1 = __shfl(score, base+1),
                        s2 = __shfl(score, base+2), s3 = __shfl(score, base+3);
            float best = s0 + trj0; int bi = 0;
            float v = s1 + trj1; if (v > best) { best = v; bi = 1; }
            v = s2 + trj2; if (v > best) { best = v; bi = 2; }
            v = s3 + trj3; if (v > best) { best = v; bi = 3; }
            score = best + e;
            bp_sh[b_loc][s][j] = (unsigned char)bi;
        }
        const float fv = score + end_t[j];
        const float f0 = __shfl(fv, base+0), f1 = __shfl(fv, base+1),
                    f2 = __shfl(fv, base+2), f3 = __shfl(fv, base+3);
        __syncthreads();
        if (j == 0) {   // backtrack (first-occurrence argmax, like jnp)
            float best = f0; int tag = 0;
            if (f1 > best) { best = f1; tag = 1; }
            if (f2 > best) { best = f2; tag = 2; }
            if (f3 > best) { best = f3; tag = 3; }
            tag_sh[b_loc][Ss-1] = (unsigned char)tag;
            for (int s = Ss - 1; s >= 1; --s) {
                tag = bp_sh[b_loc][s][tag];
                tag_sh[b_loc][s-1] = (unsigned char)tag;
            }
        }
        __syncthreads();
        for (int idx = t; idx < 16 * Ss; idx += 64) {
            const int bl = idx >> 9, s = idx & (Ss - 1);
            out_tags[(size_t)(blk*16 + bl) * Ss + s] = (float)tag_sh[bl][s];
        }
    } else {
        const int b = (blk - 4) * 16 + b_loc;
        const float trj0 = trans[0*4+j], trj1 = trans[1*4+j],
                    trj2 = trans[2*4+j], trj3 = trans[3*4+j];
        const float blj = blin[j];
        float alpha = start_t[j] + blj
                    + EM4(0,0,b,j) + EM4(1,0,b,j) + EM4(2,0,b,j) + EM4(3,0,b,j);
        for (int s = 1; s < Ss; ++s) {
            const float e = EM4(0,s,b,j) + EM4(1,s,b,j) + EM4(2,s,b,j) + EM4(3,s,b,j) + blj;
            const float a0 = __shfl(alpha, base+0), a1 = __shfl(alpha, base+1),
                        a2 = __shfl(alpha, base+2), a3 = __shfl(alpha, base+3);
            const float x0 = a0 + trj0, x1 = a1 + trj1, x2 = a2 + trj2, x3 = a3 + trj3;
            const float m = fmaxf(fmaxf(x0, x1), fmaxf(x2, x3));
            alpha = m + logf(expf(x0-m) + expf(x1-m) + expf(x2-m) + expf(x3-m)) + e;
        }
        const float dv = alpha + end_t[j];
        const float d0 = __shfl(dv, base+0), d1 = __shfl(dv, base+1),
                    d2 = __shfl(dv, base+2), d3 = __shfl(dv, base+3);
        const float dm = fmaxf(fmaxf(d0, d1), fmaxf(d2, d3));
        const float denom = dm + logf(expf(d0-dm) + expf(d1-dm) + expf(d2-dm) + expf(d3-dm));

        const int lo = j * 128, hi = lo + 128;
        float num = 0.f;
        int tprev = (lo > 0) ? tags[(size_t)b*Ss + lo - 1] : 0;
        if (j == 0) num += start_t[tags[(size_t)b*Ss]];
        if (j == 3) num += end_t[tags[(size_t)b*Ss + Ss - 1]];
        for (int s = lo; s < hi; ++s) {
            const int tg = tags[(size_t)b*Ss + s];
            num += EM4(0,s,b,tg) + EM4(1,s,b,tg) + EM4(2,s,b,tg) + EM4(3,s,b,tg) + blin[tg];
            if (s > 0) num += trans[tprev*4 + tg];
            tprev = tg;
        }
        num += __shfl_xor(num, 1);
        num += __shfl_xor(num, 2);
        float lb = (j == 0) ? (denom - num) : 0.f;
        #pragma unroll
        for (int off = 32; off > 0; off >>= 1) lb += __shfl_down(lb, off);
        if (t == 0) atomicAdd(out_loss, lb);
    }
}

// ---------------------------------------------------------------------------
extern "C" void kernel_launch(void* const* d_in, const int* in_sizes, int n_in,
                              void* d_out, int out_size, void* d_ws, size_t ws_size,
                              hipStream_t stream)
{
    const int*   sentence = (const int*)d_in[0];
    const int*   tags     = (const int*)d_in[1];
    const float* emb      = (const float*)d_in[3];
    const float* Wih_f    = (const float*)d_in[4];
    const float* Whh_f    = (const float*)d_in[5];
    const float* b_f      = (const float*)d_in[6];
    const float* Wih_b    = (const float*)d_in[7];
    const float* Whh_b    = (const float*)d_in[8];
    const float* b_b      = (const float*)d_in[9];
    const float* Wlin     = (const float*)d_in[10];
    const float* blin     = (const float*)d_in[11];
    const float* start_t  = (const float*)d_in[12];
    const float* end_t    = (const float*)d_in[13];
    const float* trans    = (const float*)d_in[14];

    // workspace layout (floats)
    float*        embproj = (float*)d_ws;                      // 16,384,000
    float*        WihP    = embproj + 2 * EPROJ_PER_DIR;       // 524,288 (reused)
    unsigned int* W16q    = (unsigned int*)(WihP + 2 * WMAT_PER_DIR);  // 262,144 u32
    float*        bP      = (float*)(W16q + 262144);           // 2048
    float*        WlinQ   = bP + 2048;                         // 2048
    float*        emisP   = WlinQ + 2048;                      // 4*512*64*4 = 524,288

    // WihP region dead after the GEMM -> flags + h exchange
    int*          flags  = (int*)WihP;                         // 512 ints
    unsigned int* hgbuf  = (unsigned int*)(WihP + 1024);       // 64*2*2*128 u32

    prep_kernel<<<2048, 256, 0, stream>>>(Wih_f, Whh_f, b_f, Wih_b, Whh_b, b_b, Wlin,
                                          WihP, W16q, bP, WlinQ);
    dim3 gg(Vv / BM, 1024 / BN, 2);
    embproj_gemm<<<gg, 256, 0, stream>>>(emb, WihP, bP, embproj);

    hipMemsetAsync(flags, 0, 512 * sizeof(int), stream);

    const int* k_sent = sentence;
    const float* k_ep = embproj;
    const unsigned int* k_w16 = W16q;
    const float* k_wlin = WlinQ;
    unsigned int* k_hg = hgbuf;
    int* k_fl = flags;
    float* k_em = emisP;
    void* args[] = { (void*)&k_sent, (void*)&k_ep, (void*)&k_w16, (void*)&k_wlin,
                     (void*)&k_hg, (void*)&k_fl, (void*)&k_em };
    hipLaunchCooperativeKernel((const void*)lstm_pair_kernel, dim3(128), dim3(512),
                               args, 0, stream);

    float* out = (float*)d_out;
    float* out_loss = out + Bb * Ss;
    hipMemsetAsync(out_loss, 0, sizeof(float), stream);
    tail_kernel<<<8, 64, 0, stream>>>(emisP, blin, start_t, end_t, trans,
                                      tags, out, out_loss);
}